// Round 2
// baseline (633.169 us; speedup 1.0000x reference)
//
#include <hip/hip_runtime.h>
#include <hip/hip_bf16.h>

// Problem constants (fixed by the reference).
#define BB 32
#define CC 32
#define PP 4096      // H*W
#define KS 9
#define KK 64        // output channels
#define CK 288       // C*KS

// ---- dtype detector: is x packed bf16 or fp32? ----
// Low 16 bits of each 32-bit word: for bf16-packed x they are a real
// ~N(0,1) bf16 (exponent field in [112,130] w.p. ~1); for fp32 x they are
// uniform mantissa bits (in-range w.p. ~7%). Count over 256 words.
__global__ void detect_kernel(const unsigned int* __restrict__ xw,
                              int* __restrict__ flag) {
    if (blockIdx.x == 0 && threadIdx.x == 0) {
        int cnt = 0;
        for (int i = 0; i < 256; ++i) {
            unsigned int e = (xw[i] >> 7) & 0xFFu;   // exponent of low bf16
            if (e >= 112u && e <= 130u) ++cnt;
        }
        *flag = (cnt >= 128) ? 1 : 0;   // 1 = bf16, 0 = fp32
    }
}

// ---- prep: weights -> fp32 workspace (convert or copy per flag) ----
__global__ void prep_w_kernel(const void* __restrict__ w,
                              float* __restrict__ wf,
                              const int* __restrict__ flag, int n) {
    int i = blockIdx.x * blockDim.x + threadIdx.x;
    if (i >= n) return;
    if (*flag)
        wf[i] = __bfloat162float(((const __hip_bfloat16*)w)[i]);
    else
        wf[i] = ((const float*)w)[i];
}

// ---- main: one thread computes 8 output channels for one (b, p) ----
// tid -> p = tid & 4095, grp = (tid>>12)&7, b = tid>>15
// out[b, grp*8+i, p] = sum_c sum_k W[grp*8+i, c*9+k] * x[b, c, idx[p,k]]
__global__ __launch_bounds__(256)
void abc_gather_kernel(const void* __restrict__ x,
                       const float* __restrict__ wf,
                       const int* __restrict__ idx,
                       void* __restrict__ out,
                       const int* __restrict__ flag) {
    const int tid = blockIdx.x * 256 + threadIdx.x;
    const int p   = tid & (PP - 1);
    const int r   = tid >> 12;
    const int grp = r & 7;
    const int b   = r >> 3;
    const int ko0 = grp * 8;
    const int isbf = flag ? *flag : 0;   // wave-uniform

    // neighbor indices for this pixel (shared across all c, b)
    int q[KS];
#pragma unroll
    for (int k = 0; k < KS; ++k) q[k] = idx[p * KS + k];

    float acc[8];
#pragma unroll
    for (int i = 0; i < 8; ++i) acc[i] = 0.0f;

#pragma unroll 1
    for (int c = 0; c < CC; ++c) {
        // gather 9 neighbors from x[b, c, :] (row is L1-resident)
        float xv[KS];
        const size_t row = (size_t)(b * CC + c) * PP;
        if (isbf) {
            const __hip_bfloat16* xr = (const __hip_bfloat16*)x + row;
#pragma unroll
            for (int k = 0; k < KS; ++k) xv[k] = __bfloat162float(xr[q[k]]);
        } else {
            const float* xr = (const float*)x + row;
#pragma unroll
            for (int k = 0; k < KS; ++k) xv[k] = xr[q[k]];
        }

        const int wbase = ko0 * CK + c * KS;
#pragma unroll
        for (int i = 0; i < 8; ++i) {
            const int ro = wbase + i * CK;
#pragma unroll
            for (int k = 0; k < KS; ++k)
                acc[i] += xv[k] * wf[ro + k];
        }
    }

    // out[b, ko0+i, p] — format mirrors input flag
    const size_t obase = ((size_t)(b * KK + ko0)) * PP + p;
    if (isbf) {
        __hip_bfloat16* o = (__hip_bfloat16*)out;
#pragma unroll
        for (int i = 0; i < 8; ++i)
            o[obase + (size_t)i * PP] = __float2bfloat16(acc[i]);
    } else {
        float* o = (float*)out;
#pragma unroll
        for (int i = 0; i < 8; ++i)
            o[obase + (size_t)i * PP] = acc[i];
    }
}

extern "C" void kernel_launch(void* const* d_in, const int* in_sizes, int n_in,
                              void* d_out, int out_size, void* d_ws, size_t ws_size,
                              hipStream_t stream) {
    const void* x  = d_in[0];
    const void* w  = d_in[1];
    const int* idx = (const int*)d_in[2];

    const int n_w = KK * CK;                       // 18432
    const size_t need = 16 + (size_t)n_w * sizeof(float);

    const int total_threads = BB * 8 * PP;         // 1,048,576
    const int nblocks = total_threads / 256;       // 4096

    if (ws_size >= need) {
        int*   flag = (int*)d_ws;
        float* wf   = (float*)((char*)d_ws + 16);
        detect_kernel<<<1, 64, 0, stream>>>((const unsigned int*)x, flag);
        prep_w_kernel<<<(n_w + 255) / 256, 256, 0, stream>>>(w, wf, flag, n_w);
        abc_gather_kernel<<<nblocks, 256, 0, stream>>>(x, wf, idx, d_out, flag);
    } else {
        // no scratch: assume fp32, read weights directly
        abc_gather_kernel<<<nblocks, 256, 0, stream>>>(x, (const float*)w, idx,
                                                       d_out, nullptr);
    }
}

// Round 3
// 187.229 us; speedup vs baseline: 3.3818x; 3.3818x over previous
//
#include <hip/hip_runtime.h>
#include <hip/hip_bf16.h>

// Problem constants (fixed by the reference).
#define BB 32
#define CC 32
#define PP 4096      // H*W
#define KS 9
#define KK 64        // output channels
#define CK 288       // C*KS
#define TP 256       // pixels per block

// ---- prep: transpose weights w[ko][c*9+k] -> w2[c*9+k][ko] (fp32) ----
__global__ void prep_wt_kernel(const float* __restrict__ w,
                               float* __restrict__ w2, int n) {
    int i = blockIdx.x * blockDim.x + threadIdx.x;   // i = ck*64 + ko
    if (i >= n) return;
    int ko = i & (KK - 1);
    int ck = i >> 6;
    w2[i] = w[ko * CK + ck];
}

// ---- main ----
// grid = B * (P/TP) = 32*16 = 512 blocks, 256 threads.
// Block (b, tile): thread t owns pixel p = tile*TP + t, computes all 64
// output channels. Per c: stage x[b,c,:] (16 KB) into LDS coalesced, then
// 9 LDS gathers + 576 FMAs vs wave-uniform (scalar-loaded) weights.
template <bool WT>
__global__ __launch_bounds__(256)
void abc_main_kernel(const float* __restrict__ x,
                     const float* __restrict__ w,     // WT ? w2[ck][ko] : w[ko][ck]
                     const int* __restrict__ idx,
                     float* __restrict__ out) {
    __shared__ float xrow[PP];
    const int t   = threadIdx.x;
    const int blk = blockIdx.x;
    const int b   = blk >> 4;           // 16 tiles per batch
    const int p   = ((blk & 15) * TP) + t;

    int q[KS];
#pragma unroll
    for (int k = 0; k < KS; ++k) q[k] = idx[p * KS + k];

    float acc[KK];
#pragma unroll
    for (int i = 0; i < KK; ++i) acc[i] = 0.0f;

    const float* xb = x + (size_t)b * CC * PP;

#pragma unroll 1
    for (int c = 0; c < CC; ++c) {
        // stage x[b,c,:] -> LDS, coalesced float4
        const float4* src = (const float4*)(xb + (size_t)c * PP);
        float4* dst = (float4*)xrow;
#pragma unroll
        for (int j = 0; j < PP / (4 * TP); ++j)
            dst[j * TP + t] = src[j * TP + t];
        __syncthreads();

        float xv[KS];
#pragma unroll
        for (int k = 0; k < KS; ++k) xv[k] = xrow[q[k]];

#pragma unroll
        for (int k = 0; k < KS; ++k) {
            if (WT) {
                const float* wc = w + (c * KS + k) * KK;   // contiguous in ko
#pragma unroll
                for (int ko = 0; ko < KK; ++ko)
                    acc[ko] += xv[k] * wc[ko];
            } else {
                const int col = c * KS + k;
#pragma unroll
                for (int ko = 0; ko < KK; ++ko)
                    acc[ko] += xv[k] * w[ko * CK + col];
            }
        }
        __syncthreads();
    }

    // out[b, ko, p]: per-ko writes are lane-coalesced (1 KB contiguous)
    float* ob = out + (size_t)b * KK * PP + p;
#pragma unroll
    for (int ko = 0; ko < KK; ++ko)
        ob[(size_t)ko * PP] = acc[ko];
}

extern "C" void kernel_launch(void* const* d_in, const int* in_sizes, int n_in,
                              void* d_out, int out_size, void* d_ws, size_t ws_size,
                              hipStream_t stream) {
    const float* x  = (const float*)d_in[0];
    const float* w  = (const float*)d_in[1];
    const int* idx  = (const int*)d_in[2];
    float* out      = (float*)d_out;

    const int n_w = KK * CK;                        // 18432
    const int nblocks = BB * (PP / TP);             // 512

    if (ws_size >= (size_t)n_w * sizeof(float)) {
        float* w2 = (float*)d_ws;
        prep_wt_kernel<<<(n_w + 255) / 256, 256, 0, stream>>>(w, w2, n_w);
        abc_main_kernel<true><<<nblocks, 256, 0, stream>>>(x, w2, idx, out);
    } else {
        abc_main_kernel<false><<<nblocks, 256, 0, stream>>>(x, w, idx, out);
    }
}

// Round 4
// 98.405 us; speedup vs baseline: 6.4343x; 1.9026x over previous
//
#include <hip/hip_runtime.h>
#include <hip/hip_bf16.h>

// Problem constants (fixed by the reference).
#define BB 32
#define CC 32
#define PP 4096      // H*W
#define KS 9
#define KK 64        // output channels
#define CK 288       // C*KS

typedef __attribute__((ext_vector_type(8))) short short8;
typedef __attribute__((ext_vector_type(4))) float float4v;

__device__ inline unsigned short f2bf(float f) {
    __hip_bfloat16 h = __float2bfloat16(f);
    return __builtin_bit_cast(unsigned short, h);
}

// ---- prep 1: x[b][c][p] fp32 -> xt[b][p][c] bf16 (pixel-major rows) ----
__global__ __launch_bounds__(256)
void prep_xt_kernel(const float* __restrict__ x, unsigned short* __restrict__ xt) {
    const int t = threadIdx.x;
    const int b = blockIdx.x >> 4;
    const int p = ((blockIdx.x & 15) << 8) + t;
    const float* xb = x + (size_t)b * CC * PP + p;
    unsigned int buf[16];
#pragma unroll
    for (int c2 = 0; c2 < 16; ++c2) {
        float lo = xb[(size_t)(2 * c2) * PP];
        float hi = xb[(size_t)(2 * c2 + 1) * PP];
        buf[c2] = (unsigned int)f2bf(lo) | ((unsigned int)f2bf(hi) << 16);
    }
    uint4* dst = (uint4*)(xt + ((size_t)b * PP + p) * CC);
    const uint4* s = (const uint4*)buf;
#pragma unroll
    for (int j = 0; j < 4; ++j) dst[j] = s[j];
}

// ---- prep 2: W[ko][c*9+k] fp32 -> Wb bf16 in MFMA B-fragment order ----
// K reordered as ck' = k*32 + c. Fragment flat index:
// i = ((kc*4 + nt)*64 + lane)*8 + j  ->  B[k'=kc*32+(lane>>4)*8+j][n=nt*16+(lane&15)]
__global__ void prep_wb_kernel(const float* __restrict__ w,
                               unsigned short* __restrict__ wb, int n) {
    int i = blockIdx.x * blockDim.x + threadIdx.x;
    if (i >= n) return;
    int j  = i & 7;
    int l  = (i >> 3) & 63;
    int nt = (i >> 9) & 3;
    int kc = i >> 11;                 // = neighbor k
    int c  = ((l >> 4) << 3) + j;
    int nn = (nt << 4) + (l & 15);
    wb[i] = f2bf(w[nn * CK + c * KS + kc]);
}

// ---- main: per block = (b, 64-pixel tile), 4 waves, MFMA 16x16x32 ----
__global__ __launch_bounds__(256)
void abc_mfma_kernel(const unsigned short* __restrict__ xt,
                     const unsigned short* __restrict__ wb,
                     const int* __restrict__ idx,
                     float* __restrict__ out) {
    __shared__ char smem[74752];
    unsigned short* As = (unsigned short*)smem;            // 64 x 296 bf16 = 37888 B
    unsigned short* Bs = (unsigned short*)(smem + 37888);  // 36864 B fragment-order W
    float* Cs = (float*)smem;                              // 64 x 68 fp32, aliases As

    const int t  = threadIdx.x;
    const int b  = blockIdx.x >> 6;          // 64 tiles per batch
    const int p0 = (blockIdx.x & 63) << 6;   // 64 pixels per tile

    // load Bs (2304 uint4)
    {
        const uint4* src = (const uint4*)wb;
        uint4* dst = (uint4*)Bs;
#pragma unroll
        for (int j = 0; j < 9; ++j) dst[j * 256 + t] = src[j * 256 + t];
    }
    // stage As: 576 gathers x 4 16B-chunks; chunk id -> (gather g, sub)
    {
#pragma unroll
        for (int j = 0; j < 9; ++j) {
            int id  = j * 256 + t;
            int g   = id >> 2, sub = id & 3;
            int pl  = g / 9;
            int k   = g - pl * 9;
            int q   = idx[(p0 + pl) * KS + k];
            const uint4* src = (const uint4*)(xt + ((size_t)b * PP + q) * CC + (sub << 3));
            *(uint4*)(&As[pl * 296 + k * 32 + (sub << 3)]) = *src;
        }
    }
    __syncthreads();

    const int l    = t & 63;
    const int w    = t >> 6;      // wave id = m-tile (16 pixels each)
    const int lo16 = l & 15;
    const int quad = l >> 4;

    float4v acc[4] = {{0,0,0,0},{0,0,0,0},{0,0,0,0},{0,0,0,0}};

#pragma unroll
    for (int kc = 0; kc < 9; ++kc) {
        short8 a = *(const short8*)(&As[(w * 16 + lo16) * 296 + kc * 32 + quad * 8]);
#pragma unroll
        for (int nt = 0; nt < 4; ++nt) {
            short8 bf = *(const short8*)(&Bs[(((kc * 4 + nt) * 64) + l) * 8]);
            acc[nt] = __builtin_amdgcn_mfma_f32_16x16x32_bf16(a, bf, acc[nt], 0, 0, 0);
        }
    }
    __syncthreads();   // all waves done reading As before aliasing as Cs

    // acc (C-layout: n=lane&15, m=quad*4+r) -> Cs[n][m], pad 68
#pragma unroll
    for (int nt = 0; nt < 4; ++nt)
#pragma unroll
        for (int r = 0; r < 4; ++r)
            Cs[(nt * 16 + lo16) * 68 + (w * 16 + quad * 4 + r)] = acc[nt][r];
    __syncthreads();

    // out[b][ko][p0 + m], coalesced float4
    float* ob = out + (size_t)b * KK * PP + p0;
#pragma unroll
    for (int j = 0; j < 4; ++j) {
        int fid = j * 256 + t;
        int ko  = fid >> 4, pm = fid & 15;
        float4v v = *(const float4v*)(&Cs[ko * 68 + pm * 4]);
        *(float4v*)(ob + (size_t)ko * PP + pm * 4) = v;
    }
}

// ---- fallback (ws too small): round-2 VALU kernel, weights direct ----
__global__ __launch_bounds__(256)
void abc_valu_kernel(const float* __restrict__ x, const float* __restrict__ w,
                     const int* __restrict__ idx, float* __restrict__ out) {
    __shared__ float xrow[PP];
    const int t = threadIdx.x;
    const int b = blockIdx.x >> 4;
    const int p = ((blockIdx.x & 15) << 8) + t;
    int q[KS];
#pragma unroll
    for (int k = 0; k < KS; ++k) q[k] = idx[p * KS + k];
    float acc[KK];
#pragma unroll
    for (int i = 0; i < KK; ++i) acc[i] = 0.0f;
    const float* xb = x + (size_t)b * CC * PP;
#pragma unroll 1
    for (int c = 0; c < CC; ++c) {
        const float4* src = (const float4*)(xb + (size_t)c * PP);
        float4* dst = (float4*)xrow;
#pragma unroll
        for (int j = 0; j < 4; ++j) dst[j * 256 + t] = src[j * 256 + t];
        __syncthreads();
        float xv[KS];
#pragma unroll
        for (int k = 0; k < KS; ++k) xv[k] = xrow[q[k]];
#pragma unroll
        for (int k = 0; k < KS; ++k) {
            const int col = c * KS + k;
#pragma unroll
            for (int ko = 0; ko < KK; ++ko)
                acc[ko] += xv[k] * w[ko * CK + col];
        }
        __syncthreads();
    }
    float* ob = out + (size_t)b * KK * PP + p;
#pragma unroll
    for (int ko = 0; ko < KK; ++ko)
        ob[(size_t)ko * PP] = acc[ko];
}

extern "C" void kernel_launch(void* const* d_in, const int* in_sizes, int n_in,
                              void* d_out, int out_size, void* d_ws, size_t ws_size,
                              hipStream_t stream) {
    const float* x  = (const float*)d_in[0];
    const float* w  = (const float*)d_in[1];
    const int* idx  = (const int*)d_in[2];
    float* out      = (float*)d_out;

    const size_t xt_bytes = (size_t)BB * PP * CC * 2;    // 8,388,608
    const size_t wb_off   = xt_bytes;
    const size_t need     = xt_bytes + (size_t)KK * CK * 2;

    if (ws_size >= need) {
        unsigned short* xt = (unsigned short*)d_ws;
        unsigned short* wbp = (unsigned short*)((char*)d_ws + wb_off);
        prep_xt_kernel<<<BB * (PP / 256), 256, 0, stream>>>(x, xt);
        prep_wb_kernel<<<(KK * CK + 255) / 256, 256, 0, stream>>>(w, wbp, KK * CK);
        abc_mfma_kernel<<<BB * (PP / 64), 256, 0, stream>>>(xt, wbp, idx, out);
    } else {
        abc_valu_kernel<<<BB * (PP / 256), 256, 0, stream>>>(x, w, idx, out);
    }
}

// Round 5
// 96.974 us; speedup vs baseline: 6.5293x; 1.0148x over previous
//
#include <hip/hip_runtime.h>
#include <hip/hip_bf16.h>

// Problem constants (fixed by the reference).
#define BB 32
#define CC 32
#define PP 4096      // H*W
#define KS 9
#define KK 64        // output channels
#define CK 288       // C*KS

typedef __attribute__((ext_vector_type(8))) short short8;
typedef __attribute__((ext_vector_type(4))) float float4v;

__device__ inline unsigned short f2bf(float f) {
    __hip_bfloat16 h = __float2bfloat16(f);
    return __builtin_bit_cast(unsigned short, h);
}

// ---- prep (merged): blocks [0,512) transpose x -> xt bf16 pixel-major;
//      blocks [512,584) swizzle W -> wa bf16 in MFMA A-fragment order.
// A-frag flat: i = ((kc*4 + mt)*64 + lane)*8 + j
//   -> A[m=ko=mt*16+(lane&15)][k'=kc*32+(lane>>4)*8+j],  W-elem = w[ko][c*9+kc], c=(lane>>4)*8+j
__global__ __launch_bounds__(256)
void prep_kernel(const float* __restrict__ x, const float* __restrict__ w,
                 unsigned short* __restrict__ xt, unsigned short* __restrict__ wa) {
    const int t = threadIdx.x;
    const int blk = blockIdx.x;
    if (blk < 512) {
        const int b = blk >> 4;
        const int p = ((blk & 15) << 8) + t;
        const float* xb = x + (size_t)b * CC * PP + p;
        unsigned int buf[16];
#pragma unroll
        for (int c2 = 0; c2 < 16; ++c2) {
            float lo = xb[(size_t)(2 * c2) * PP];
            float hi = xb[(size_t)(2 * c2 + 1) * PP];
            buf[c2] = (unsigned int)f2bf(lo) | ((unsigned int)f2bf(hi) << 16);
        }
        uint4* dst = (uint4*)(xt + ((size_t)b * PP + p) * CC);
        const uint4* s = (const uint4*)buf;
#pragma unroll
        for (int j = 0; j < 4; ++j) dst[j] = s[j];
    } else {
        int i = (blk - 512) * 256 + t;
        if (i < KK * CK) {
            int j  = i & 7;
            int l  = (i >> 3) & 63;
            int mt = (i >> 9) & 3;
            int kc = i >> 11;                 // = neighbor k
            int c  = ((l >> 4) << 3) + j;
            int ko = (mt << 4) + (l & 15);
            wa[i] = f2bf(w[ko * CK + c * KS + kc]);
        }
    }
}

// ---- main: LDS-free. Wave = 32 pixels x 64 ko. A = W (fragment-order,
// L1-hot), B = gathered xt rows (16B/lane direct from global). ----
__global__ __launch_bounds__(256)
void abc_mfma2_kernel(const unsigned short* __restrict__ xt,
                      const unsigned short* __restrict__ wa,
                      const int* __restrict__ idx,
                      float* __restrict__ out) {
    const int t    = threadIdx.x;
    const int l    = t & 63;
    const int w    = t >> 6;
    const int b    = blockIdx.x >> 5;            // 32 tiles of 128 pixels per batch
    const int p0   = ((blockIdx.x & 31) << 7) + (w << 5);   // wave's 32 pixels
    const int lo16 = l & 15;
    const int quad = l >> 4;

    const unsigned short* xtb = xt + (size_t)b * PP * CC;

    float4v acc[8];   // [mt][nt] -> acc[mt*2+nt]
#pragma unroll
    for (int i = 0; i < 8; ++i) acc[i] = (float4v){0.f, 0.f, 0.f, 0.f};

#pragma unroll 3
    for (int kc = 0; kc < 9; ++kc) {
        // B fragments: gather 16B chunk of the neighbor's channel row
        short8 bf[2];
#pragma unroll
        for (int nt = 0; nt < 2; ++nt) {
            const int pl = p0 + nt * 16 + lo16;
            const int q  = idx[pl * KS + kc];
            bf[nt] = *(const short8*)(xtb + (size_t)q * CC + (quad << 3));
        }
        // A fragments: W in fragment order, contiguous per lane (L1-hot)
        const short8* wf = (const short8*)(wa) + (kc * 4) * 64 + l;
#pragma unroll
        for (int mt = 0; mt < 4; ++mt) {
            short8 a = wf[mt * 64];
#pragma unroll
            for (int nt = 0; nt < 2; ++nt)
                acc[mt * 2 + nt] =
                    __builtin_amdgcn_mfma_f32_16x16x32_bf16(a, bf[nt], acc[mt * 2 + nt], 0, 0, 0);
        }
    }

    // D layout: m(ko_sub)=quad*4+r, n(pixel)=lo16. 64B-segment stores.
    float* ob = out + (size_t)b * KK * PP + p0 + lo16;
#pragma unroll
    for (int mt = 0; mt < 4; ++mt) {
        float* om = ob + (size_t)(mt * 16 + quad * 4) * PP;
#pragma unroll
        for (int r = 0; r < 4; ++r)
#pragma unroll
            for (int nt = 0; nt < 2; ++nt)
                om[(size_t)r * PP + nt * 16] = acc[mt * 2 + nt][r];
    }
}

// ---- fallback (ws too small): round-2 VALU kernel ----
__global__ __launch_bounds__(256)
void abc_valu_kernel(const float* __restrict__ x, const float* __restrict__ w,
                     const int* __restrict__ idx, float* __restrict__ out) {
    __shared__ float xrow[PP];
    const int t = threadIdx.x;
    const int b = blockIdx.x >> 4;
    const int p = ((blockIdx.x & 15) << 8) + t;
    int q[KS];
#pragma unroll
    for (int k = 0; k < KS; ++k) q[k] = idx[p * KS + k];
    float acc[KK];
#pragma unroll
    for (int i = 0; i < KK; ++i) acc[i] = 0.0f;
    const float* xb = x + (size_t)b * CC * PP;
#pragma unroll 1
    for (int c = 0; c < CC; ++c) {
        const float4* src = (const float4*)(xb + (size_t)c * PP);
        float4* dst = (float4*)xrow;
#pragma unroll
        for (int j = 0; j < 4; ++j) dst[j * 256 + t] = src[j * 256 + t];
        __syncthreads();
        float xv[KS];
#pragma unroll
        for (int k = 0; k < KS; ++k) xv[k] = xrow[q[k]];
#pragma unroll
        for (int k = 0; k < KS; ++k) {
            const int col = c * KS + k;
#pragma unroll
            for (int ko = 0; ko < KK; ++ko)
                acc[ko] += xv[k] * w[ko * CK + col];
        }
        __syncthreads();
    }
    float* ob = out + (size_t)b * KK * PP + p;
#pragma unroll
    for (int ko = 0; ko < KK; ++ko)
        ob[(size_t)ko * PP] = acc[ko];
}

extern "C" void kernel_launch(void* const* d_in, const int* in_sizes, int n_in,
                              void* d_out, int out_size, void* d_ws, size_t ws_size,
                              hipStream_t stream) {
    const float* x  = (const float*)d_in[0];
    const float* w  = (const float*)d_in[1];
    const int* idx  = (const int*)d_in[2];
    float* out      = (float*)d_out;

    const size_t xt_bytes = (size_t)BB * PP * CC * 2;    // 8,388,608
    const size_t need     = xt_bytes + (size_t)KK * CK * 2;

    if (ws_size >= need) {
        unsigned short* xt = (unsigned short*)d_ws;
        unsigned short* wa = (unsigned short*)((char*)d_ws + xt_bytes);
        const int wb_blocks = (KK * CK + 255) / 256;     // 72
        prep_kernel<<<512 + wb_blocks, 256, 0, stream>>>(x, w, xt, wa);
        abc_mfma2_kernel<<<BB * (PP / 128), 256, 0, stream>>>(xt, wa, idx, out);
    } else {
        abc_valu_kernel<<<BB * (PP / 256), 256, 0, stream>>>(x, w, idx, out);
    }
}